// Round 8
// baseline (37.485 us; speedup 1.0000x reference)
//
#include <hip/hip_runtime.h>
#include <math.h>

namespace {
constexpr int N = 512;
constexpr int DIN = 128;
constexpr int PROJ = 128;
constexpr int H = 4;
constexpr int E = 32;          // per-head dim
constexpr int KF = 64;         // ENC/2 frequencies
constexpr int FEAT = E + 2*KF; // 160 A-features per head: [q | P | Q]
constexpr float SCALE = 0.17677669529663687f; // 1/sqrt(32)
constexpr int TI = 8;          // i-rows per attn block
constexpr int JQ = 4;          // j-chunks
constexpr int CHUNK = 128;     // j per chunk
}

__device__ __forceinline__ float wave_max(float v) {
  #pragma unroll
  for (int o = 32; o > 0; o >>= 1) v = fmaxf(v, __shfl_xor(v, o, 64));
  return v;
}
__device__ __forceinline__ float wave_sum(float v) {
  #pragma unroll
  for (int o = 32; o > 0; o >>= 1) v += __shfl_xor(v, o, 64);
  return v;
}

// ---- kernel 1: projections + features, balanced blocks ----
// bx in [0,384): mat = bx>>7 (0..2), 4-row tiles.
// bx in [384,640): mat3 (qt) + feature work, 2-row tiles.
__global__ __launch_bounds__(256)
void proj_feat_kernel(const float* __restrict__ inp,
                      const float* __restrict__ pos, const float* __restrict__ f,
                      const float* __restrict__ Wq, const float* __restrict__ bq,
                      const float* __restrict__ Wk, const float* __restrict__ bk,
                      const float* __restrict__ Wv, const float* __restrict__ bv,
                      const float* __restrict__ Wqt, const float* __restrict__ bqt,
                      const float* __restrict__ Wt, const float* __restrict__ bt,
                      float* __restrict__ Afeat, float* __restrict__ BTk,
                      float* __restrict__ Vmat, float* __restrict__ Btrig,
                      float* __restrict__ c0)
{
  const int bx = blockIdx.x;
  const int t = threadIdx.x;
  const int c = t & 127;

  if (bx < 384) {
    const int mat = bx >> 7, rowTile = bx & 127;
    const int i0 = rowTile * 4;
    const int half = t >> 7;
    __shared__ float x[4][DIN];
    #pragma unroll
    for (int r = 0; r < 2; ++r) {
      const int id = t + r * 256;
      x[id >> 7][id & 127] = inp[i0 * DIN + id];
    }
    const float* W; const float* bvec;
    switch (mat) {
      case 0:  W = Wq; bvec = bq; break;
      case 1:  W = Wk; bvec = bk; break;
      default: W = Wv; bvec = bv; break;
    }
    __syncthreads();
    const int r0 = half * 2, r1 = r0 + 1;
    float a0 = 0.f, a1 = 0.f;
    #pragma unroll 8
    for (int d = 0; d < DIN; d += 2) {
      const float w0 = W[d * PROJ + c];
      const float w1 = W[(d + 1) * PROJ + c];
      const float2 x0 = *(const float2*)&x[r0][d];
      const float2 x1 = *(const float2*)&x[r1][d];
      a0 += w0 * x0.x + w1 * x0.y;
      a1 += w0 * x1.x + w1 * x1.y;
    }
    const float bb = bvec[c];
    a0 += bb; a1 += bb;
    const int h = c >> 5, e = c & 31;
    const int row0 = i0 + r0, row1 = i0 + r1;
    if (mat == 0) {
      Afeat[(h * N + row0) * FEAT + e] = a0;
      Afeat[(h * N + row1) * FEAT + e] = a1;
    } else if (mat == 1) {
      BTk[(size_t)(h * E + e) * N + row0] = a0;
      BTk[(size_t)(h * E + e) * N + row1] = a1;
    } else {
      Vmat[(h * N + row0) * E + e] = a0;
      Vmat[(h * N + row1) * E + e] = a1;
    }
    return;
  }

  // ---- mat3 + feature blocks: 2 rows each ----
  const int i0 = (bx - 384) * 2;
  const int r = t >> 7;   // 0/1 row for proj phase
  __shared__ float x[2][DIN];
  __shared__ float qt_l[2][PROJ];
  __shared__ float ss[2][KF], sc[2][KF];
  __shared__ float ul[2][H][PROJ];

  x[r][c] = inp[i0 * DIN + t];
  if (t < 128) {
    const int rr = t >> 6, k = t & 63;
    float s_, c_;
    sincosf(pos[i0 + rr] * f[k], &s_, &c_);
    ss[rr][k] = s_; sc[rr][k] = c_;
  }
  __syncthreads();

  {
    float a = 0.f;
    #pragma unroll 8
    for (int d = 0; d < DIN; d += 2) {
      const float w0 = Wqt[d * PROJ + c];
      const float w1 = Wqt[(d + 1) * PROJ + c];
      const float2 xv = *(const float2*)&x[r][d];
      a += w0 * xv.x + w1 * xv.y;
    }
    qt_l[r][c] = a + bqt[c];
  }
  __syncthreads();

  // u[r][h][c] = Wt[c]·qt[r] per head; each thread does 2 heads x 2 rows
  {
    const int g = t >> 7;  // heads 2g, 2g+1
    const float* wrow = &Wt[c * PROJ];
    #pragma unroll
    for (int hh = 2 * g; hh < 2 * g + 2; ++hh) {
      float uA = 0.f, uB = 0.f;
      #pragma unroll
      for (int e4 = 0; e4 < E; e4 += 4) {
        const float4 w = *(const float4*)&wrow[hh * E + e4];
        const float4 qA = *(const float4*)&qt_l[0][hh * E + e4];
        const float4 qB = *(const float4*)&qt_l[1][hh * E + e4];
        uA += w.x * qA.x + w.y * qA.y + w.z * qA.z + w.w * qA.w;
        uB += w.x * qB.x + w.y * qB.y + w.z * qB.z + w.w * qB.w;
      }
      ul[0][hh][c] = uA;
      ul[1][hh][c] = uB;
    }
  }
  if (t < 8) {  // c0[h,i] = bt[h*E:]·qt[h*E:]
    const int rr = t & 1, hh = t >> 1;
    float acc = 0.f;
    for (int e2 = 0; e2 < E; ++e2) acc += bt[hh * E + e2] * qt_l[rr][hh * E + e2];
    c0[hh * N + i0 + rr] = acc;
  }
  __syncthreads();

  {
    const int k = t & 63, hh = t >> 6;
    #pragma unroll
    for (int rr = 0; rr < 2; ++rr) {
      const float u0 = ul[rr][hh][2 * k], u1 = ul[rr][hh][2 * k + 1];
      const float s_ = ss[rr][k], c_ = sc[rr][k];
      Afeat[(hh * N + i0 + rr) * FEAT + E + k]      =  u0 * s_ + u1 * c_;  // pairs cos_j
      Afeat[(hh * N + i0 + rr) * FEAT + E + KF + k] = -u0 * c_ + u1 * s_;  // pairs sin_j
      if (hh == 0) {
        Btrig[k * N + i0 + rr]        = c_;
        Btrig[(KF + k) * N + i0 + rr] = s_;
      }
    }
  }
}

// ---- kernel 2: flash-style partial attention over a 128-j chunk ----
// 4 waves x 2 rows; 2 j's per lane via float2 B loads.
__global__ __launch_bounds__(256)
void attn_partial(const float* __restrict__ Afeat, const float* __restrict__ BTk,
                  const float* __restrict__ Btrig, const float* __restrict__ Vmat,
                  const float* __restrict__ c0,
                  float* __restrict__ Po, float* __restrict__ Pm,
                  float* __restrict__ Ps)
{
  const int b = blockIdx.x, h = blockIdx.y, q = blockIdx.z;
  const int i0 = b * TI, jbase = q * CHUNK;
  if (jbase > i0) return;   // chunk entirely above diagonal
  const int t = threadIdx.x;
  const int lane = t & 63;
  const int rh = __builtin_amdgcn_readfirstlane(t >> 6);  // wave -> rows 2rh, 2rh+1
  const int j0 = jbase + 2 * lane, j1 = j0 + 1;

  __shared__ float pT[CHUNK][13];     // [j][row] padded (6.7 KB)
  __shared__ float obuf[16][TI][34];  // padded (17.4 KB)

  const float* A0 = Afeat + (size_t)(h * N + i0 + rh * 2) * FEAT;  // wave-uniform
  const float* A1 = A0 + FEAT;
  const float cc0 = c0[h * N + i0 + rh * 2];
  const float cc1 = c0[h * N + i0 + rh * 2 + 1];

  float acc00 = 0.f, acc01 = 0.f, acc10 = 0.f, acc11 = 0.f;  // [row][jj]
  {
    const float* Bp = BTk + (size_t)h * E * N + j0;
    #pragma unroll
    for (int d = 0; d < E; d += 4) {
      const float2 b0 = *(const float2*)&Bp[(size_t)(d + 0) * N];
      const float2 b1 = *(const float2*)&Bp[(size_t)(d + 1) * N];
      const float2 b2 = *(const float2*)&Bp[(size_t)(d + 2) * N];
      const float2 b3 = *(const float2*)&Bp[(size_t)(d + 3) * N];
      const float4 a0 = *(const float4*)&A0[d];
      const float4 a1 = *(const float4*)&A1[d];
      acc00 += a0.x * b0.x + a0.y * b1.x + a0.z * b2.x + a0.w * b3.x;
      acc01 += a0.x * b0.y + a0.y * b1.y + a0.z * b2.y + a0.w * b3.y;
      acc10 += a1.x * b0.x + a1.y * b1.x + a1.z * b2.x + a1.w * b3.x;
      acc11 += a1.x * b0.y + a1.y * b1.y + a1.z * b2.y + a1.w * b3.y;
    }
  }
  {
    const float* Bp = Btrig + j0;
    #pragma unroll 8
    for (int d = 0; d < 2 * KF; d += 4) {
      const float2 b0 = *(const float2*)&Bp[(size_t)(d + 0) * N];
      const float2 b1 = *(const float2*)&Bp[(size_t)(d + 1) * N];
      const float2 b2 = *(const float2*)&Bp[(size_t)(d + 2) * N];
      const float2 b3 = *(const float2*)&Bp[(size_t)(d + 3) * N];
      const float4 a0 = *(const float4*)&A0[E + d];
      const float4 a1 = *(const float4*)&A1[E + d];
      acc00 += a0.x * b0.x + a0.y * b1.x + a0.z * b2.x + a0.w * b3.x;
      acc01 += a0.x * b0.y + a0.y * b1.y + a0.z * b2.y + a0.w * b3.y;
      acc10 += a1.x * b0.x + a1.y * b1.x + a1.z * b2.x + a1.w * b3.x;
      acc11 += a1.x * b0.y + a1.y * b1.y + a1.z * b2.y + a1.w * b3.y;
    }
  }

  const int i_0 = i0 + rh * 2, i_1 = i_0 + 1;
  const float s00 = (j0 <= i_0) ? (acc00 + cc0) * SCALE : -INFINITY;
  const float s01 = (j1 <= i_0) ? (acc01 + cc0) * SCALE : -INFINITY;
  const float s10 = (j0 <= i_1) ? (acc10 + cc1) * SCALE : -INFINITY;
  const float s11 = (j1 <= i_1) ? (acc11 + cc1) * SCALE : -INFINITY;

  const float m0 = wave_max(fmaxf(s00, s01));
  const float m1 = wave_max(fmaxf(s10, s11));
  const float p00 = __expf(s00 - m0), p01 = __expf(s01 - m0);
  const float p10 = __expf(s10 - m1), p11 = __expf(s11 - m1);
  const float sum0 = wave_sum(p00 + p01);
  const float sum1 = wave_sum(p10 + p11);

  *(float2*)&pT[2 * lane    ][rh * 2] = make_float2(p00, p10);
  *(float2*)&pT[2 * lane + 1][rh * 2] = make_float2(p01, p11);
  if (lane == 0) {
    const int base = (h * N + i_0) * JQ + q;
    Pm[base]      = m0; Ps[base]      = sum0;
    Pm[base + JQ] = m1; Ps[base + JQ] = sum1;
  }
  __syncthreads();

  // PV partial: thread owns e-pair, group gg covers jl = gg, gg+16, ...
  const int e2 = (t & 15) * 2, gg = t >> 4;
  float2 o[TI];
  #pragma unroll
  for (int r = 0; r < TI; ++r) o[r] = make_float2(0.f, 0.f);
  const float* Vh = Vmat + ((size_t)h * N + jbase) * E + e2;
  #pragma unroll
  for (int it = 0; it < CHUNK / 16; ++it) {
    const int jl = gg + 16 * it;
    const float2 vv = *(const float2*)&Vh[jl * E];
    const float4 pa = *(const float4*)&pT[jl][0];
    const float4 pb = *(const float4*)&pT[jl][4];
    o[0].x += pa.x * vv.x; o[0].y += pa.x * vv.y;
    o[1].x += pa.y * vv.x; o[1].y += pa.y * vv.y;
    o[2].x += pa.z * vv.x; o[2].y += pa.z * vv.y;
    o[3].x += pa.w * vv.x; o[3].y += pa.w * vv.y;
    o[4].x += pb.x * vv.x; o[4].y += pb.x * vv.y;
    o[5].x += pb.y * vv.x; o[5].y += pb.y * vv.y;
    o[6].x += pb.z * vv.x; o[6].y += pb.z * vv.y;
    o[7].x += pb.w * vv.x; o[7].y += pb.w * vv.y;
  }
  #pragma unroll
  for (int r = 0; r < TI; ++r) *(float2*)&obuf[gg][r][e2] = o[r];
  __syncthreads();
  {
    const int r = t >> 5, e = t & 31;
    float tot = 0.f;
    #pragma unroll
    for (int g2 = 0; g2 < 16; ++g2) tot += obuf[g2][r][e];
    Po[((size_t)(h * N + i0 + r) * JQ + q) * E + e] = tot;
  }
}

// ---- kernel 3: combine partials (exact softmax merge) ----
__global__ __launch_bounds__(256)
void attn_combine(const float* __restrict__ Po, const float* __restrict__ Pm,
                  const float* __restrict__ Ps, float* __restrict__ out)
{
  const int gid = blockIdx.x * 256 + threadIdx.x;   // 0..65535
  const int task = gid >> 5, e = gid & 31;          // task = h*N + i
  const int h = task >> 9, i = task & (N - 1);
  const int nq = (i >> 7) + 1;
  float m = -INFINITY;
  for (int qq = 0; qq < nq; ++qq) m = fmaxf(m, Pm[task * JQ + qq]);
  float s = 0.f, o = 0.f;
  for (int qq = 0; qq < nq; ++qq) {
    const float w = __expf(Pm[task * JQ + qq] - m);
    s += Ps[task * JQ + qq] * w;
    o += Po[(size_t)(task * JQ + qq) * E + e] * w;
  }
  out[i * PROJ + h * E + e] = o / s;
}

extern "C" void kernel_launch(void* const* d_in, const int* in_sizes, int n_in,
                              void* d_out, int out_size, void* d_ws, size_t ws_size,
                              hipStream_t stream) {
  const float* inp = (const float*)d_in[0];
  const float* pos = (const float*)d_in[1];
  const float* f   = (const float*)d_in[2];
  const float* Wq  = (const float*)d_in[3];
  const float* bq  = (const float*)d_in[4];
  const float* Wk  = (const float*)d_in[5];
  const float* bk  = (const float*)d_in[6];
  const float* Wv  = (const float*)d_in[7];
  const float* bv  = (const float*)d_in[8];
  const float* Wqt = (const float*)d_in[9];
  const float* bqt = (const float*)d_in[10];
  const float* Wt  = (const float*)d_in[11];
  const float* bt  = (const float*)d_in[12];
  float* out = (float*)d_out;

  float* ws    = (float*)d_ws;
  float* Afeat = ws;                          // H*N*FEAT   = 327680
  float* BTk   = Afeat + H * N * FEAT;        // H*E*N      = 65536
  float* Btrig = BTk + (size_t)H * E * N;     // 2*KF*N     = 65536
  float* Vmat  = Btrig + 2 * KF * N;          // H*N*E      = 65536
  float* c0    = Vmat + H * N * E;            // H*N        = 2048
  float* Po    = c0 + H * N;                  // H*N*JQ*E   = 262144
  float* Pm    = Po + (size_t)H * N * JQ * E; // H*N*JQ     = 8192
  float* Ps    = Pm + H * N * JQ;             // 8192

  proj_feat_kernel<<<640, 256, 0, stream>>>(inp, pos, f, Wq, bq, Wk, bk, Wv, bv,
                                            Wqt, bqt, Wt, bt,
                                            Afeat, BTk, Vmat, Btrig, c0);
  attn_partial<<<dim3(N / TI, H, JQ), 256, 0, stream>>>(Afeat, BTk, Btrig, Vmat,
                                                        c0, Po, Pm, Ps);
  attn_combine<<<H * N * E / 256, 256, 0, stream>>>(Po, Pm, Ps, out);
}

// Round 9
// 36.632 us; speedup vs baseline: 1.0233x; 1.0233x over previous
//
#include <hip/hip_runtime.h>
#include <math.h>

namespace {
constexpr int N = 512;
constexpr int DIN = 128;
constexpr int PROJ = 128;
constexpr int H = 4;
constexpr int E = 32;          // per-head dim
constexpr int KF = 64;         // ENC/2 frequencies
constexpr int FEAT = E + 2*KF; // 160 A-features per head: [q | P | Q]
constexpr float SCALE = 0.17677669529663687f; // 1/sqrt(32)
constexpr int TI = 4;          // i-rows per attn block (1 row per wave)
constexpr int JQ = 8;          // j-chunks
constexpr int CHUNK = 64;      // j per chunk
}

__device__ __forceinline__ float wave_max(float v) {
  #pragma unroll
  for (int o = 32; o > 0; o >>= 1) v = fmaxf(v, __shfl_xor(v, o, 64));
  return v;
}
__device__ __forceinline__ float wave_sum(float v) {
  #pragma unroll
  for (int o = 32; o > 0; o >>= 1) v += __shfl_xor(v, o, 64);
  return v;
}

// ---- kernel 1: projections + (for mat==3 blocks) full feature computation ----
// 512 blocks: rowTile = bx & 127 (4 rows each), mat = bx >> 7   [round-7 exact]
__global__ __launch_bounds__(256)
void proj_feat_kernel(const float* __restrict__ inp,
                      const float* __restrict__ pos, const float* __restrict__ f,
                      const float* __restrict__ Wq, const float* __restrict__ bq,
                      const float* __restrict__ Wk, const float* __restrict__ bk,
                      const float* __restrict__ Wv, const float* __restrict__ bv,
                      const float* __restrict__ Wqt, const float* __restrict__ bqt,
                      const float* __restrict__ Wt, const float* __restrict__ bt,
                      float* __restrict__ Afeat, float* __restrict__ BTk,
                      float* __restrict__ Vmat, float* __restrict__ Btrig,
                      float* __restrict__ c0)
{
  const int bx = blockIdx.x;
  const int t = threadIdx.x;
  const int rowTile = bx & 127, mat = bx >> 7;
  const int i0 = rowTile * 4;
  const int c = t & 127, half = t >> 7;

  __shared__ float x[4][DIN];
  __shared__ float qt_l[4][PROJ];
  __shared__ float ss[4][KF], sc[4][KF];
  __shared__ float ul[4][H][PROJ];

  #pragma unroll
  for (int r = 0; r < 2; ++r) {
    const int id = t + r * 256;
    x[id >> 7][id & 127] = inp[i0 * DIN + id];
  }
  const float* W; const float* bvec;
  switch (mat) {
    case 0:  W = Wq;  bvec = bq;  break;
    case 1:  W = Wk;  bvec = bk;  break;
    case 2:  W = Wv;  bvec = bv;  break;
    default: W = Wqt; bvec = bqt; break;
  }
  __syncthreads();

  const int r0 = half * 2, r1 = r0 + 1;
  float a0 = 0.f, a1 = 0.f;
  #pragma unroll 8
  for (int d = 0; d < DIN; d += 2) {
    const float w0 = W[d * PROJ + c];
    const float w1 = W[(d + 1) * PROJ + c];
    const float2 x0 = *(const float2*)&x[r0][d];
    const float2 x1 = *(const float2*)&x[r1][d];
    a0 += w0 * x0.x + w1 * x0.y;
    a1 += w0 * x1.x + w1 * x1.y;
  }
  const float bb = bvec[c];
  a0 += bb; a1 += bb;
  const int h = c >> 5, e = c & 31;
  const int row0 = i0 + r0, row1 = i0 + r1;
  if (mat == 0) {
    Afeat[(h * N + row0) * FEAT + e] = a0;
    Afeat[(h * N + row1) * FEAT + e] = a1;
    return;
  } else if (mat == 1) {
    BTk[(size_t)(h * E + e) * N + row0] = a0;
    BTk[(size_t)(h * E + e) * N + row1] = a1;
    return;
  } else if (mat == 2) {
    Vmat[(h * N + row0) * E + e] = a0;
    Vmat[(h * N + row1) * E + e] = a1;
    return;
  }
  // mat == 3: qt stays in LDS; this block also does the feature work
  qt_l[r0][c] = a0;
  qt_l[r1][c] = a1;
  {
    const int r = t >> 6, k = t & 63;
    float s_, c_;
    sincosf(pos[i0 + r] * f[k], &s_, &c_);
    ss[r][k] = s_; sc[r][k] = c_;
  }
  __syncthreads();

  // u[r][h][c] = sum_e Wt[c][h*E+e] * qt[r][h*E+e]  (per-lane float4 rows of Wt)
  {
    const int g = t >> 7;              // rows 2g, 2g+1
    const float* wrow = &Wt[c * PROJ];
    #pragma unroll
    for (int hh = 0; hh < H; ++hh) {
      float uA = 0.f, uB = 0.f;
      #pragma unroll
      for (int e4 = 0; e4 < E; e4 += 4) {
        const float4 w = *(const float4*)&wrow[hh * E + e4];
        const float4 qA = *(const float4*)&qt_l[2 * g][hh * E + e4];
        const float4 qB = *(const float4*)&qt_l[2 * g + 1][hh * E + e4];
        uA += w.x * qA.x + w.y * qA.y + w.z * qA.z + w.w * qA.w;
        uB += w.x * qB.x + w.y * qB.y + w.z * qB.z + w.w * qB.w;
      }
      ul[2 * g][hh][c] = uA;
      ul[2 * g + 1][hh][c] = uB;
    }
  }
  if (t < 16) {  // c0[h,i] = bt[h*E:]·qt[h*E:]
    const int r = t >> 2, hh = t & 3;
    float acc = 0.f;
    for (int e2 = 0; e2 < E; ++e2) acc += bt[hh * E + e2] * qt_l[r][hh * E + e2];
    c0[hh * N + i0 + r] = acc;
  }
  __syncthreads();

  {
    const int k = t & 63, hh = t >> 6;
    #pragma unroll
    for (int r = 0; r < 4; ++r) {
      const float u0 = ul[r][hh][2 * k], u1 = ul[r][hh][2 * k + 1];
      const float s_ = ss[r][k], c_ = sc[r][k];
      Afeat[(hh * N + i0 + r) * FEAT + E + k]      =  u0 * s_ + u1 * c_;  // pairs cos_j
      Afeat[(hh * N + i0 + r) * FEAT + E + KF + k] = -u0 * c_ + u1 * s_;  // pairs sin_j
      if (hh == 0) {
        Btrig[k * N + i0 + r]        = c_;
        Btrig[(KF + k) * N + i0 + r] = s_;
      }
    }
  }
}

// ---- kernel 2: partial attention, ONE row per wave (max occupancy) ----
__global__ __launch_bounds__(256)
void attn_partial(const float* __restrict__ Afeat, const float* __restrict__ BTk,
                  const float* __restrict__ Btrig, const float* __restrict__ Vmat,
                  const float* __restrict__ c0,
                  float* __restrict__ Po, float* __restrict__ Pm,
                  float* __restrict__ Ps)
{
  const int b = blockIdx.x, h = blockIdx.y, q = blockIdx.z;
  const int i0 = b * TI, jbase = q * CHUNK;
  if (jbase > i0) return;   // chunk entirely above diagonal
  const int t = threadIdx.x;
  const int lane = t & 63;
  const int w = __builtin_amdgcn_readfirstlane(t >> 6);  // wave id = local row
  const int i = i0 + w;
  const int j = jbase + lane;

  __shared__ float pT[CHUNK][12];     // [j][row] padded (3 KB)
  __shared__ float obuf[16][TI][34];  // (8.7 KB)

  const float* A0 = Afeat + (size_t)(h * N + i) * FEAT;  // wave-uniform -> s_load
  const float cc = c0[h * N + i];

  float acc = 0.f;
  {
    const float* Bp = BTk + (size_t)h * E * N + j;
    #pragma unroll
    for (int d = 0; d < E; d += 4) {
      const float b0 = Bp[(size_t)(d + 0) * N];
      const float b1 = Bp[(size_t)(d + 1) * N];
      const float b2 = Bp[(size_t)(d + 2) * N];
      const float b3 = Bp[(size_t)(d + 3) * N];
      const float4 a = *(const float4*)&A0[d];
      acc += a.x * b0 + a.y * b1 + a.z * b2 + a.w * b3;
    }
  }
  {
    const float* Bp = Btrig + j;
    #pragma unroll 8
    for (int d = 0; d < 2 * KF; d += 4) {
      const float b0 = Bp[(size_t)(d + 0) * N];
      const float b1 = Bp[(size_t)(d + 1) * N];
      const float b2 = Bp[(size_t)(d + 2) * N];
      const float b3 = Bp[(size_t)(d + 3) * N];
      const float4 a = *(const float4*)&A0[E + d];
      acc += a.x * b0 + a.y * b1 + a.z * b2 + a.w * b3;
    }
  }

  const float s = (j <= i) ? (acc + cc) * SCALE : -INFINITY;
  const float m = wave_max(s);
  const float p = __expf(s - m);
  const float sum = wave_sum(p);

  pT[lane][w] = p;
  if (lane == 0) {
    const int base = (h * N + i) * JQ + q;
    Pm[base] = m; Ps[base] = sum;
  }
  __syncthreads();

  // PV partial: thread owns e-pair, group gg covers jl = gg, gg+16, ...
  const int e2 = (t & 15) * 2, gg = t >> 4;
  float2 o[TI];
  #pragma unroll
  for (int r = 0; r < TI; ++r) o[r] = make_float2(0.f, 0.f);
  const float* Vh = Vmat + ((size_t)h * N + jbase) * E + e2;
  #pragma unroll
  for (int it = 0; it < CHUNK / 16; ++it) {
    const int jl = gg + 16 * it;
    const float2 vv = *(const float2*)&Vh[jl * E];
    const float4 pa = *(const float4*)&pT[jl][0];
    o[0].x += pa.x * vv.x; o[0].y += pa.x * vv.y;
    o[1].x += pa.y * vv.x; o[1].y += pa.y * vv.y;
    o[2].x += pa.z * vv.x; o[2].y += pa.z * vv.y;
    o[3].x += pa.w * vv.x; o[3].y += pa.w * vv.y;
  }
  #pragma unroll
  for (int r = 0; r < TI; ++r) *(float2*)&obuf[gg][r][e2] = o[r];
  __syncthreads();
  if (t < 128) {
    const int r = t >> 5, e = t & 31;
    float tot = 0.f;
    #pragma unroll
    for (int g2 = 0; g2 < 16; ++g2) tot += obuf[g2][r][e];
    Po[((size_t)(h * N + i0 + r) * JQ + q) * E + e] = tot;
  }
}

// ---- kernel 3: combine partials (exact softmax merge) ----
__global__ __launch_bounds__(256)
void attn_combine(const float* __restrict__ Po, const float* __restrict__ Pm,
                  const float* __restrict__ Ps, float* __restrict__ out)
{
  const int gid = blockIdx.x * 256 + threadIdx.x;   // 0..65535
  const int task = gid >> 5, e = gid & 31;          // task = h*N + i
  const int h = task >> 9, i = task & (N - 1);
  const int nq = (i >> 6) + 1;
  float m = -INFINITY;
  for (int qq = 0; qq < nq; ++qq) m = fmaxf(m, Pm[task * JQ + qq]);
  float s = 0.f, o = 0.f;
  for (int qq = 0; qq < nq; ++qq) {
    const float w = __expf(Pm[task * JQ + qq] - m);
    s += Ps[task * JQ + qq] * w;
    o += Po[(size_t)(task * JQ + qq) * E + e] * w;
  }
  out[i * PROJ + h * E + e] = o / s;
}

extern "C" void kernel_launch(void* const* d_in, const int* in_sizes, int n_in,
                              void* d_out, int out_size, void* d_ws, size_t ws_size,
                              hipStream_t stream) {
  const float* inp = (const float*)d_in[0];
  const float* pos = (const float*)d_in[1];
  const float* f   = (const float*)d_in[2];
  const float* Wq  = (const float*)d_in[3];
  const float* bq  = (const float*)d_in[4];
  const float* Wk  = (const float*)d_in[5];
  const float* bk  = (const float*)d_in[6];
  const float* Wv  = (const float*)d_in[7];
  const float* bv  = (const float*)d_in[8];
  const float* Wqt = (const float*)d_in[9];
  const float* bqt = (const float*)d_in[10];
  const float* Wt  = (const float*)d_in[11];
  const float* bt  = (const float*)d_in[12];
  float* out = (float*)d_out;

  float* ws    = (float*)d_ws;
  float* Afeat = ws;                          // H*N*FEAT   = 327680
  float* BTk   = Afeat + H * N * FEAT;        // H*E*N      = 65536
  float* Btrig = BTk + (size_t)H * E * N;     // 2*KF*N     = 65536
  float* Vmat  = Btrig + 2 * KF * N;          // H*N*E      = 65536
  float* c0    = Vmat + H * N * E;            // H*N        = 2048
  float* Po    = c0 + H * N;                  // H*N*JQ*E   = 524288
  float* Pm    = Po + (size_t)H * N * JQ * E; // H*N*JQ     = 16384
  float* Ps    = Pm + H * N * JQ;             // 16384

  proj_feat_kernel<<<512, 256, 0, stream>>>(inp, pos, f, Wq, bq, Wk, bk, Wv, bv,
                                            Wqt, bqt, Wt, bt,
                                            Afeat, BTk, Vmat, Btrig, c0);
  attn_partial<<<dim3(N / TI, H, JQ), 256, 0, stream>>>(Afeat, BTk, Btrig, Vmat,
                                                        c0, Po, Pm, Ps);
  attn_combine<<<H * N * E / 256, 256, 0, stream>>>(Po, Pm, Ps, out);
}

// Round 10
// 28.197 us; speedup vs baseline: 1.3294x; 1.2991x over previous
//
#include <hip/hip_runtime.h>
#include <math.h>

namespace {
constexpr int N = 512;
constexpr int DIN = 128;
constexpr int PROJ = 128;
constexpr int H = 4;
constexpr int E = 32;          // per-head dim
constexpr int KF = 64;         // ENC/2 frequencies
constexpr int FEAT = E + 2*KF; // 160 A-features per head: [q | P | Q]
constexpr float SCALE = 0.17677669529663687f; // 1/sqrt(32)
constexpr int TI = 8;          // i-rows per attn block
constexpr int JQ = 8;          // j-chunks
constexpr int CHUNK = 64;      // j per chunk
}

__device__ __forceinline__ float wave_max(float v) {
  #pragma unroll
  for (int o = 32; o > 0; o >>= 1) v = fmaxf(v, __shfl_xor(v, o, 64));
  return v;
}
__device__ __forceinline__ float wave_sum(float v) {
  #pragma unroll
  for (int o = 32; o > 0; o >>= 1) v += __shfl_xor(v, o, 64);
  return v;
}

// ---- kernel 1: projections + features, balanced blocks ----
// bx in [0,384): mat = bx>>7 (0..2), 4-row tiles.
// bx in [384,640): mat3 (qt) + feature work, 2-row tiles (~equal work/block).
__global__ __launch_bounds__(256)
void proj_feat_kernel(const float* __restrict__ inp,
                      const float* __restrict__ pos, const float* __restrict__ f,
                      const float* __restrict__ Wq, const float* __restrict__ bq,
                      const float* __restrict__ Wk, const float* __restrict__ bk,
                      const float* __restrict__ Wv, const float* __restrict__ bv,
                      const float* __restrict__ Wqt, const float* __restrict__ bqt,
                      const float* __restrict__ Wt, const float* __restrict__ bt,
                      float* __restrict__ Afeat, float* __restrict__ BTk,
                      float* __restrict__ Vmat, float* __restrict__ Btrig,
                      float* __restrict__ c0)
{
  const int bx = blockIdx.x;
  const int t = threadIdx.x;
  const int c = t & 127;

  if (bx < 384) {
    const int mat = bx >> 7, rowTile = bx & 127;
    const int i0 = rowTile * 4;
    const int half = t >> 7;
    __shared__ float x[4][DIN];
    #pragma unroll
    for (int r = 0; r < 2; ++r) {
      const int id = t + r * 256;
      x[id >> 7][id & 127] = inp[i0 * DIN + id];
    }
    const float* W; const float* bvec;
    switch (mat) {
      case 0:  W = Wq; bvec = bq; break;
      case 1:  W = Wk; bvec = bk; break;
      default: W = Wv; bvec = bv; break;
    }
    __syncthreads();
    const int r0 = half * 2, r1 = r0 + 1;
    float a0 = 0.f, a1 = 0.f;
    #pragma unroll 8
    for (int d = 0; d < DIN; d += 2) {
      const float w0 = W[d * PROJ + c];
      const float w1 = W[(d + 1) * PROJ + c];
      const float2 x0 = *(const float2*)&x[r0][d];
      const float2 x1 = *(const float2*)&x[r1][d];
      a0 += w0 * x0.x + w1 * x0.y;
      a1 += w0 * x1.x + w1 * x1.y;
    }
    const float bb = bvec[c];
    a0 += bb; a1 += bb;
    const int h = c >> 5, e = c & 31;
    const int row0 = i0 + r0, row1 = i0 + r1;
    if (mat == 0) {
      Afeat[(h * N + row0) * FEAT + e] = a0;
      Afeat[(h * N + row1) * FEAT + e] = a1;
    } else if (mat == 1) {
      BTk[(size_t)(h * E + e) * N + row0] = a0;
      BTk[(size_t)(h * E + e) * N + row1] = a1;
    } else {
      Vmat[(h * N + row0) * E + e] = a0;
      Vmat[(h * N + row1) * E + e] = a1;
    }
    return;
  }

  // ---- mat3 + feature blocks: 2 rows each ----
  const int i0 = (bx - 384) * 2;
  const int r = t >> 7;   // 0/1 row for proj phase
  __shared__ float x[2][DIN];
  __shared__ float qt_l[2][PROJ];
  __shared__ float ss[2][KF], sc[2][KF];
  __shared__ float ul[2][H][PROJ];

  x[r][c] = inp[i0 * DIN + t];
  if (t < 128) {
    const int rr = t >> 6, k = t & 63;
    float s_, c_;
    sincosf(pos[i0 + rr] * f[k], &s_, &c_);
    ss[rr][k] = s_; sc[rr][k] = c_;
  }
  __syncthreads();

  {
    float a = 0.f;
    #pragma unroll 8
    for (int d = 0; d < DIN; d += 2) {
      const float w0 = Wqt[d * PROJ + c];
      const float w1 = Wqt[(d + 1) * PROJ + c];
      const float2 xv = *(const float2*)&x[r][d];
      a += w0 * xv.x + w1 * xv.y;
    }
    qt_l[r][c] = a + bqt[c];
  }
  __syncthreads();

  // u[r][h][c] = Wt[c]·qt[r] per head; each thread does 2 heads x 2 rows
  {
    const int g = t >> 7;  // heads 2g, 2g+1
    const float* wrow = &Wt[c * PROJ];
    #pragma unroll
    for (int hh = 2 * g; hh < 2 * g + 2; ++hh) {
      float uA = 0.f, uB = 0.f;
      #pragma unroll
      for (int e4 = 0; e4 < E; e4 += 4) {
        const float4 w = *(const float4*)&wrow[hh * E + e4];
        const float4 qA = *(const float4*)&qt_l[0][hh * E + e4];
        const float4 qB = *(const float4*)&qt_l[1][hh * E + e4];
        uA += w.x * qA.x + w.y * qA.y + w.z * qA.z + w.w * qA.w;
        uB += w.x * qB.x + w.y * qB.y + w.z * qB.z + w.w * qB.w;
      }
      ul[0][hh][c] = uA;
      ul[1][hh][c] = uB;
    }
  }
  if (t < 8) {  // c0[h,i] = bt[h*E:]·qt[h*E:]
    const int rr = t & 1, hh = t >> 1;
    float acc = 0.f;
    for (int e2 = 0; e2 < E; ++e2) acc += bt[hh * E + e2] * qt_l[rr][hh * E + e2];
    c0[hh * N + i0 + rr] = acc;
  }
  __syncthreads();

  {
    const int k = t & 63, hh = t >> 6;
    #pragma unroll
    for (int rr = 0; rr < 2; ++rr) {
      const float u0 = ul[rr][hh][2 * k], u1 = ul[rr][hh][2 * k + 1];
      const float s_ = ss[rr][k], c_ = sc[rr][k];
      Afeat[(hh * N + i0 + rr) * FEAT + E + k]      =  u0 * s_ + u1 * c_;  // pairs cos_j
      Afeat[(hh * N + i0 + rr) * FEAT + E + KF + k] = -u0 * c_ + u1 * s_;  // pairs sin_j
      if (hh == 0) {
        Btrig[k * N + i0 + rr]        = c_;
        Btrig[(KF + k) * N + i0 + rr] = s_;
      }
    }
  }
}

// ---- kernel 2: flash-style partial attention over a 64-j chunk (round-7 exact) ----
__global__ __launch_bounds__(256)
void attn_partial(const float* __restrict__ Afeat, const float* __restrict__ BTk,
                  const float* __restrict__ Btrig, const float* __restrict__ Vmat,
                  const float* __restrict__ c0,
                  float* __restrict__ Po, float* __restrict__ Pm,
                  float* __restrict__ Ps)
{
  const int b = blockIdx.x, h = blockIdx.y, q = blockIdx.z;
  const int i0 = b * TI, jbase = q * CHUNK;
  if (jbase > i0) return;   // chunk entirely above diagonal
  const int t = threadIdx.x;
  const int lane = t & 63;
  const int rh = __builtin_amdgcn_readfirstlane(t >> 6);  // wave -> rows 2rh, 2rh+1
  const int j = jbase + lane;

  __shared__ float pT[CHUNK][12];     // [j][row] padded
  __shared__ float obuf[16][TI][32];

  const float* A0 = Afeat + (size_t)(h * N + i0 + rh * 2) * FEAT;  // wave-uniform
  const float* A1 = A0 + FEAT;
  const float cc0 = c0[h * N + i0 + rh * 2];
  const float cc1 = c0[h * N + i0 + rh * 2 + 1];

  float acc0 = 0.f, acc1 = 0.f;
  {
    const float* Bp = BTk + (size_t)h * E * N + j;
    #pragma unroll
    for (int d = 0; d < E; d += 4) {
      const float b0 = Bp[(size_t)(d + 0) * N];
      const float b1 = Bp[(size_t)(d + 1) * N];
      const float b2 = Bp[(size_t)(d + 2) * N];
      const float b3 = Bp[(size_t)(d + 3) * N];
      const float4 a0 = *(const float4*)&A0[d];
      const float4 a1 = *(const float4*)&A1[d];
      acc0 += a0.x * b0 + a0.y * b1 + a0.z * b2 + a0.w * b3;
      acc1 += a1.x * b0 + a1.y * b1 + a1.z * b2 + a1.w * b3;
    }
  }
  {
    const float* Bp = Btrig + j;
    #pragma unroll 8
    for (int d = 0; d < 2 * KF; d += 4) {
      const float b0 = Bp[(size_t)(d + 0) * N];
      const float b1 = Bp[(size_t)(d + 1) * N];
      const float b2 = Bp[(size_t)(d + 2) * N];
      const float b3 = Bp[(size_t)(d + 3) * N];
      const float4 a0 = *(const float4*)&A0[E + d];
      const float4 a1 = *(const float4*)&A1[E + d];
      acc0 += a0.x * b0 + a0.y * b1 + a0.z * b2 + a0.w * b3;
      acc1 += a1.x * b0 + a1.y * b1 + a1.z * b2 + a1.w * b3;
    }
  }

  const int i_0 = i0 + rh * 2, i_1 = i_0 + 1;
  const float s0 = (j <= i_0) ? (acc0 + cc0) * SCALE : -INFINITY;
  const float s1 = (j <= i_1) ? (acc1 + cc1) * SCALE : -INFINITY;

  const float m0 = wave_max(s0);
  const float m1 = wave_max(s1);
  const float p0 = __expf(s0 - m0);
  const float p1 = __expf(s1 - m1);
  const float sum0 = wave_sum(p0);
  const float sum1 = wave_sum(p1);

  *(float2*)&pT[lane][rh * 2] = make_float2(p0, p1);
  if (lane == 0) {
    const int base = (h * N + i_0) * JQ + q;
    Pm[base]      = m0; Ps[base]      = sum0;
    Pm[base + JQ] = m1; Ps[base + JQ] = sum1;
  }
  __syncthreads();

  // PV partial: thread owns e-pair, group gg covers jl = gg, gg+16, ...
  const int e2 = (t & 15) * 2, gg = t >> 4;
  float2 o[TI];
  #pragma unroll
  for (int r = 0; r < TI; ++r) o[r] = make_float2(0.f, 0.f);
  const float* Vh = Vmat + ((size_t)h * N + jbase) * E + e2;
  #pragma unroll
  for (int it = 0; it < CHUNK / 16; ++it) {
    const int jl = gg + 16 * it;
    const float2 vv = *(const float2*)&Vh[jl * E];
    const float4 pa = *(const float4*)&pT[jl][0];
    const float4 pb = *(const float4*)&pT[jl][4];
    o[0].x += pa.x * vv.x; o[0].y += pa.x * vv.y;
    o[1].x += pa.y * vv.x; o[1].y += pa.y * vv.y;
    o[2].x += pa.z * vv.x; o[2].y += pa.z * vv.y;
    o[3].x += pa.w * vv.x; o[3].y += pa.w * vv.y;
    o[4].x += pb.x * vv.x; o[4].y += pb.x * vv.y;
    o[5].x += pb.y * vv.x; o[5].y += pb.y * vv.y;
    o[6].x += pb.z * vv.x; o[6].y += pb.z * vv.y;
    o[7].x += pb.w * vv.x; o[7].y += pb.w * vv.y;
  }
  #pragma unroll
  for (int r = 0; r < TI; ++r) *(float2*)&obuf[gg][r][e2] = o[r];
  __syncthreads();
  {
    const int r = t >> 5, e = t & 31;
    float tot = 0.f;
    #pragma unroll
    for (int g2 = 0; g2 < 16; ++g2) tot += obuf[g2][r][e];
    Po[((size_t)(h * N + i0 + r) * JQ + q) * E + e] = tot;
  }
}

// ---- kernel 3: combine partials (exact softmax merge) ----
__global__ __launch_bounds__(256)
void attn_combine(const float* __restrict__ Po, const float* __restrict__ Pm,
                  const float* __restrict__ Ps, float* __restrict__ out)
{
  const int gid = blockIdx.x * 256 + threadIdx.x;   // 0..65535
  const int task = gid >> 5, e = gid & 31;          // task = h*N + i
  const int h = task >> 9, i = task & (N - 1);
  const int nq = (i >> 6) + 1;
  float m = -INFINITY;
  for (int qq = 0; qq < nq; ++qq) m = fmaxf(m, Pm[task * JQ + qq]);
  float s = 0.f, o = 0.f;
  for (int qq = 0; qq < nq; ++qq) {
    const float w = __expf(Pm[task * JQ + qq] - m);
    s += Ps[task * JQ + qq] * w;
    o += Po[(size_t)(task * JQ + qq) * E + e] * w;
  }
  out[i * PROJ + h * E + e] = o / s;
}

extern "C" void kernel_launch(void* const* d_in, const int* in_sizes, int n_in,
                              void* d_out, int out_size, void* d_ws, size_t ws_size,
                              hipStream_t stream) {
  const float* inp = (const float*)d_in[0];
  const float* pos = (const float*)d_in[1];
  const float* f   = (const float*)d_in[2];
  const float* Wq  = (const float*)d_in[3];
  const float* bq  = (const float*)d_in[4];
  const float* Wk  = (const float*)d_in[5];
  const float* bk  = (const float*)d_in[6];
  const float* Wv  = (const float*)d_in[7];
  const float* bv  = (const float*)d_in[8];
  const float* Wqt = (const float*)d_in[9];
  const float* bqt = (const float*)d_in[10];
  const float* Wt  = (const float*)d_in[11];
  const float* bt  = (const float*)d_in[12];
  float* out = (float*)d_out;

  float* ws    = (float*)d_ws;
  float* Afeat = ws;                          // H*N*FEAT   = 327680
  float* BTk   = Afeat + H * N * FEAT;        // H*E*N      = 65536
  float* Btrig = BTk + (size_t)H * E * N;     // 2*KF*N     = 65536
  float* Vmat  = Btrig + 2 * KF * N;          // H*N*E      = 65536
  float* c0    = Vmat + H * N * E;            // H*N        = 2048
  float* Po    = c0 + H * N;                  // H*N*JQ*E   = 524288
  float* Pm    = Po + (size_t)H * N * JQ * E; // H*N*JQ     = 16384
  float* Ps    = Pm + H * N * JQ;             // 16384

  proj_feat_kernel<<<640, 256, 0, stream>>>(inp, pos, f, Wq, bq, Wk, bk, Wv, bv,
                                            Wqt, bqt, Wt, bt,
                                            Afeat, BTk, Vmat, Btrig, c0);
  attn_partial<<<dim3(N / TI, H, JQ), 256, 0, stream>>>(Afeat, BTk, Btrig, Vmat,
                                                        c0, Po, Pm, Ps);
  attn_combine<<<H * N * E / 256, 256, 0, stream>>>(Po, Pm, Ps, out);
}